// Round 6
// baseline (253.268 us; speedup 1.0000x reference)
//
#include <hip/hip_runtime.h>

#define DIM 64
#define H1  128
#define H2  16
#define NC  4
#define VCH 5
#define IMG 224
#define PP  (IMG * IMG)   // 50176
#define BB  32

typedef float f4 __attribute__((ext_vector_type(4)));

// ws layout (floats): [0, 128) att[b][c] softmax weights

// ---------------------------------------------------------------------------
// Kernel A: per-batch prep. One block per batch (32 blocks, 256 threads):
// all 5 MLP rows (1 q + 4 k) + LayerNorm + logits + 4-way softmax.
// ---------------------------------------------------------------------------
__global__ __launch_bounds__(256) void prep_kernel(
    const float* __restrict__ q, const float* __restrict__ k,
    const int* __restrict__ md,
    const float* __restrict__ Wq1, const float* __restrict__ bq1,
    const float* __restrict__ Wq2, const float* __restrict__ bq2,
    const float* __restrict__ gq,  const float* __restrict__ betaq,
    const float* __restrict__ Wk1, const float* __restrict__ bk1,
    const float* __restrict__ Wk2, const float* __restrict__ bk2,
    const float* __restrict__ gk,  const float* __restrict__ betak,
    float* __restrict__ ws)
{
    __shared__ float xs[5][DIM];     // row 0 = q, rows 1..4 = k contrast c-1
    __shared__ float h1[5][H1];
    __shared__ float h2[5][H2];
    __shared__ float y16[5][H2];

    const int b   = blockIdx.x;
    const int tid = threadIdx.x;     // 0..255

    if (tid < DIM) xs[0][tid] = q[b * DIM + tid];
    {
        const int d = tid >> 2, c = tid & 3;
        xs[1 + c][d] = k[(b * DIM + d) * NC + c];
    }
    __syncthreads();

    for (int i = tid; i < 5 * H1; i += 256) {
        const int r = i >> 7, col = i & (H1 - 1);
        const float* W1 = (r == 0) ? Wq1 : Wk1;
        const float* b1 = (r == 0) ? bq1 : bk1;
        float acc = b1[col];
#pragma unroll 8
        for (int d = 0; d < DIM; ++d)
            acc = fmaf(xs[r][d], W1[d * H1 + col], acc);
        h1[r][col] = (acc > 0.0f) ? acc : 0.1f * acc;
    }
    __syncthreads();

    if (tid < 5 * H2) {
        const int r = tid >> 4, col = tid & (H2 - 1);
        const float* W2 = (r == 0) ? Wq2 : Wk2;
        const float* b2 = (r == 0) ? bq2 : bk2;
        float acc = b2[col];
#pragma unroll 8
        for (int i = 0; i < H1; ++i)
            acc = fmaf(h1[r][i], W2[i * H2 + col], acc);
        h2[r][col] = acc;
    }
    __syncthreads();

    if (tid < 5 * H2) {
        const int r = tid >> 4, col = tid & (H2 - 1);
        float mu = 0.0f;
#pragma unroll
        for (int j = 0; j < H2; ++j) mu += h2[r][j];
        mu *= (1.0f / H2);
        float var = 0.0f;
#pragma unroll
        for (int j = 0; j < H2; ++j) { const float d0 = h2[r][j] - mu; var += d0 * d0; }
        var *= (1.0f / H2);
        const float* g    = (r == 0) ? gq : gk;
        const float* beta = (r == 0) ? betaq : betak;
        y16[r][col] = (h2[r][col] - mu) * rsqrtf(var + 1e-5f) * g[col] + beta[col];
    }
    __syncthreads();

    if (tid < NC) {
        const int c = tid;
        float dot = 0.0f;
#pragma unroll
        for (int j = 0; j < H2; ++j) dot = fmaf(y16[0][j], y16[1 + c][j], dot);
        const float l = (dot * 0.125f - (float)md[b * NC + c] * 1.0e5f) * 0.1f;
        float m = l;
        m = fmaxf(m, __shfl_xor(m, 1, 64));
        m = fmaxf(m, __shfl_xor(m, 2, 64));
        const float e = __expf(l - m);
        float s = e;
        s += __shfl_xor(s, 1, 64);
        s += __shfl_xor(s, 2, 64);
        ws[b * NC + c] = e / s;
    }
}

// ---------------------------------------------------------------------------
// Kernel B: per-pixel fusion. 1568 blocks x 256 threads; block covers 1024
// consecutive pixels of one batch b; each thread handles 4 pixels STRIDED by
// 256 (the block width), so every VMEM instruction stays lane-dense:
// loads 64x16B contiguous, stores 64x4B contiguous. Setup (att load, softmax
// weights, base addresses) amortized 4x vs the 1-px/thread variant.
// ---------------------------------------------------------------------------
__global__ __launch_bounds__(256) void fuse_kernel(
    const float* __restrict__ v, const float* __restrict__ mask,
    const float* __restrict__ ws,
    float* __restrict__ out_fused, float* __restrict__ out_attn)
{
    const int bid = blockIdx.x;
    const int b   = bid / (PP / 1024);                 // 49 blocks per batch
    const int p0  = (bid % (PP / 1024)) * 1024 + threadIdx.x;   // +i*256

    // wave-uniform attention weights (L2-resident broadcast)
    const float* att = ws + b * NC;
    const float t0 = att[0], t1 = att[1], t2 = att[2], t3 = att[3];

    // --- masks: 4 independent dense dwordx4 nt loads, then normalize ---
    float a[4][NC];
#pragma unroll
    for (int i = 0; i < 4; ++i) {
        const int p = p0 + i * 256;
        const f4 mk = __builtin_nontemporal_load(
            reinterpret_cast<const f4*>(mask + ((size_t)b * PP + p) * NC));
        const float a0 = t0 * mk.x, a1 = t1 * mk.y,
                    a2 = t2 * mk.z, a3 = t3 * mk.w;
        const float inv = 1.0f / (a0 + a1 + a2 + a3 + 1e-8f);
        a[i][0] = a0 * inv; a[i][1] = a1 * inv;
        a[i][2] = a2 * inv; a[i][3] = a3 * inv;
    }

    // attention out: (B,C,IMG,IMG) — dense scalar stores (64x4B contiguous)
    const size_t ab = (size_t)b * NC * PP + p0;
#pragma unroll
    for (int c = 0; c < NC; ++c) {
#pragma unroll
        for (int i = 0; i < 4; ++i)
            __builtin_nontemporal_store(a[i][c],
                out_attn + ab + (size_t)c * PP + i * 256);
    }

    // fused out: (B,V_CH,IMG,IMG); v: (B,V_CH,P,C)
#pragma unroll
    for (int vc = 0; vc < VCH; ++vc) {
        const size_t vrow = (size_t)(b * VCH + vc) * PP + p0;
#pragma unroll
        for (int i = 0; i < 4; ++i) {
            const f4 vv = __builtin_nontemporal_load(
                reinterpret_cast<const f4*>(v + (vrow + i * 256) * NC));
            const float f = a[i][0] * vv.x + a[i][1] * vv.y +
                            a[i][2] * vv.z + a[i][3] * vv.w;
            __builtin_nontemporal_store(f, out_fused + vrow + i * 256);
        }
    }
}

extern "C" void kernel_launch(void* const* d_in, const int* in_sizes, int n_in,
                              void* d_out, int out_size, void* d_ws, size_t ws_size,
                              hipStream_t stream) {
    const float* q     = (const float*)d_in[0];
    const float* k     = (const float*)d_in[1];
    const float* v     = (const float*)d_in[2];
    const float* mask  = (const float*)d_in[3];
    const int*   md    = (const int*)  d_in[4];
    const float* Wq1   = (const float*)d_in[5];
    const float* bq1   = (const float*)d_in[6];
    const float* Wq2   = (const float*)d_in[7];
    const float* bq2   = (const float*)d_in[8];
    const float* gq    = (const float*)d_in[9];
    const float* betaq = (const float*)d_in[10];
    const float* Wk1   = (const float*)d_in[11];
    const float* bk1   = (const float*)d_in[12];
    const float* Wk2   = (const float*)d_in[13];
    const float* bk2   = (const float*)d_in[14];
    const float* gk    = (const float*)d_in[15];
    const float* betak = (const float*)d_in[16];

    float* ws        = (float*)d_ws;
    float* out_fused = (float*)d_out;                       // B*V_CH*P floats
    float* out_attn  = out_fused + (size_t)BB * VCH * PP;   // B*C*P floats

    hipLaunchKernelGGL(prep_kernel, dim3(BB), dim3(256), 0, stream,
                       q, k, md, Wq1, bq1, Wq2, bq2, gq, betaq,
                       Wk1, bk1, Wk2, bk2, gk, betak, ws);

    hipLaunchKernelGGL(fuse_kernel, dim3(BB * (PP / 1024)), dim3(256), 0, stream,
                       v, mask, ws, out_fused, out_attn);
}

// Round 7
// 248.820 us; speedup vs baseline: 1.0179x; 1.0179x over previous
//
#include <hip/hip_runtime.h>

#define DIM 64
#define H1  128
#define H2  16
#define NC  4
#define VCH 5
#define IMG 224
#define PP  (IMG * IMG)   // 50176
#define BB  32

typedef float f4 __attribute__((ext_vector_type(4)));

// ws layout (floats): [0, 128) att[b][c] softmax weights

// ---------------------------------------------------------------------------
// Kernel A: per-batch prep. One block per batch (32 blocks, 256 threads):
// all 5 MLP rows (1 q + 4 k) + LayerNorm + logits + 4-way softmax.
// ---------------------------------------------------------------------------
__global__ __launch_bounds__(256) void prep_kernel(
    const float* __restrict__ q, const float* __restrict__ k,
    const int* __restrict__ md,
    const float* __restrict__ Wq1, const float* __restrict__ bq1,
    const float* __restrict__ Wq2, const float* __restrict__ bq2,
    const float* __restrict__ gq,  const float* __restrict__ betaq,
    const float* __restrict__ Wk1, const float* __restrict__ bk1,
    const float* __restrict__ Wk2, const float* __restrict__ bk2,
    const float* __restrict__ gk,  const float* __restrict__ betak,
    float* __restrict__ ws)
{
    __shared__ float xs[5][DIM];     // row 0 = q, rows 1..4 = k contrast c-1
    __shared__ float h1[5][H1];
    __shared__ float h2[5][H2];
    __shared__ float y16[5][H2];

    const int b   = blockIdx.x;
    const int tid = threadIdx.x;     // 0..255

    if (tid < DIM) xs[0][tid] = q[b * DIM + tid];
    {
        const int d = tid >> 2, c = tid & 3;
        xs[1 + c][d] = k[(b * DIM + d) * NC + c];
    }
    __syncthreads();

    // layer 1: 5 rows x 128 cols = 640 outputs, 256 threads -> 3 passes.
    for (int i = tid; i < 5 * H1; i += 256) {
        const int r = i >> 7, col = i & (H1 - 1);
        const float* W1 = (r == 0) ? Wq1 : Wk1;
        const float* b1 = (r == 0) ? bq1 : bk1;
        float acc = b1[col];
#pragma unroll 8
        for (int d = 0; d < DIM; ++d)
            acc = fmaf(xs[r][d], W1[d * H1 + col], acc);
        h1[r][col] = (acc > 0.0f) ? acc : 0.1f * acc;
    }
    __syncthreads();

    // layer 2: 5 x 16 = 80 outputs
    if (tid < 5 * H2) {
        const int r = tid >> 4, col = tid & (H2 - 1);
        const float* W2 = (r == 0) ? Wq2 : Wk2;
        const float* b2 = (r == 0) ? bq2 : bk2;
        float acc = b2[col];
#pragma unroll 8
        for (int i = 0; i < H1; ++i)
            acc = fmaf(h1[r][i], W2[i * H2 + col], acc);
        h2[r][col] = acc;
    }
    __syncthreads();

    // LayerNorm per row
    if (tid < 5 * H2) {
        const int r = tid >> 4, col = tid & (H2 - 1);
        float mu = 0.0f;
#pragma unroll
        for (int j = 0; j < H2; ++j) mu += h2[r][j];
        mu *= (1.0f / H2);
        float var = 0.0f;
#pragma unroll
        for (int j = 0; j < H2; ++j) { const float d0 = h2[r][j] - mu; var += d0 * d0; }
        var *= (1.0f / H2);
        const float* g    = (r == 0) ? gq : gk;
        const float* beta = (r == 0) ? betaq : betak;
        y16[r][col] = (h2[r][col] - mu) * rsqrtf(var + 1e-5f) * g[col] + beta[col];
    }
    __syncthreads();

    // logits + softmax over contrasts
    if (tid < NC) {
        const int c = tid;
        float dot = 0.0f;
#pragma unroll
        for (int j = 0; j < H2; ++j) dot = fmaf(y16[0][j], y16[1 + c][j], dot);
        // scale = DIM^-0.5 = 0.125; modality dropout; / TEMPERATURE(10)
        const float l = (dot * 0.125f - (float)md[b * NC + c] * 1.0e5f) * 0.1f;
        float m = l;
        m = fmaxf(m, __shfl_xor(m, 1, 64));
        m = fmaxf(m, __shfl_xor(m, 2, 64));
        const float e = __expf(l - m);
        float s = e;
        s += __shfl_xor(s, 1, 64);
        s += __shfl_xor(s, 2, 64);
        ws[b * NC + c] = e / s;
    }
}

// ---------------------------------------------------------------------------
// Kernel B: per-pixel fusion (best-measured structure: 1 px/thread, dense
// coalescing). 6272 blocks x 256 threads; block covers 256 consecutive
// pixels of one batch b. No LDS, no barriers. Per thread: 6 dwordx4 nt
// loads + 9 coalesced nt stores.
// ---------------------------------------------------------------------------
__global__ __launch_bounds__(256) void fuse_kernel(
    const float* __restrict__ v, const float* __restrict__ mask,
    const float* __restrict__ ws,
    float* __restrict__ out_fused, float* __restrict__ out_attn)
{
    const int bid = blockIdx.x;
    const int b   = bid / (PP / 256);                 // 196 blocks per batch
    const int p   = (bid % (PP / 256)) * 256 + threadIdx.x;

    // wave-uniform attention weights (L2-resident broadcast)
    const float* att = ws + b * NC;
    const float t0 = att[0], t1 = att[1], t2 = att[2], t3 = att[3];

    // mask: (B,1,IMG,IMG,C) flat (b*P+p)*4
    const f4 mk = __builtin_nontemporal_load(
        reinterpret_cast<const f4*>(mask + (size_t)(b * PP + p) * NC));
    float a0 = t0 * mk.x;
    float a1 = t1 * mk.y;
    float a2 = t2 * mk.z;
    float a3 = t3 * mk.w;
    const float inv = 1.0f / (a0 + a1 + a2 + a3 + 1e-8f);
    a0 *= inv; a1 *= inv; a2 *= inv; a3 *= inv;

    // attention out: (B,C,IMG,IMG)
    const size_t ab = (size_t)b * NC * PP + p;
    __builtin_nontemporal_store(a0, out_attn + ab);
    __builtin_nontemporal_store(a1, out_attn + ab + PP);
    __builtin_nontemporal_store(a2, out_attn + ab + 2 * PP);
    __builtin_nontemporal_store(a3, out_attn + ab + 3 * PP);

    // fused out: (B,V_CH,IMG,IMG); v: (B,V_CH,P,C) flat ((b*5+vc)*P+p)*4
    const size_t vb = (size_t)b * VCH * PP + p;
#pragma unroll
    for (int vc = 0; vc < VCH; ++vc) {
        const f4 vv = __builtin_nontemporal_load(
            reinterpret_cast<const f4*>(v + (vb + (size_t)vc * PP) * NC));
        const float f = a0 * vv.x + a1 * vv.y + a2 * vv.z + a3 * vv.w;
        __builtin_nontemporal_store(f, out_fused + vb + (size_t)vc * PP);
    }
}

extern "C" void kernel_launch(void* const* d_in, const int* in_sizes, int n_in,
                              void* d_out, int out_size, void* d_ws, size_t ws_size,
                              hipStream_t stream) {
    const float* q     = (const float*)d_in[0];
    const float* k     = (const float*)d_in[1];
    const float* v     = (const float*)d_in[2];
    const float* mask  = (const float*)d_in[3];
    const int*   md    = (const int*)  d_in[4];
    const float* Wq1   = (const float*)d_in[5];
    const float* bq1   = (const float*)d_in[6];
    const float* Wq2   = (const float*)d_in[7];
    const float* bq2   = (const float*)d_in[8];
    const float* gq    = (const float*)d_in[9];
    const float* betaq = (const float*)d_in[10];
    const float* Wk1   = (const float*)d_in[11];
    const float* bk1   = (const float*)d_in[12];
    const float* Wk2   = (const float*)d_in[13];
    const float* bk2   = (const float*)d_in[14];
    const float* gk    = (const float*)d_in[15];
    const float* betak = (const float*)d_in[16];

    float* ws        = (float*)d_ws;
    float* out_fused = (float*)d_out;                       // B*V_CH*P floats
    float* out_attn  = out_fused + (size_t)BB * VCH * PP;   // B*C*P floats

    hipLaunchKernelGGL(prep_kernel, dim3(BB), dim3(256), 0, stream,
                       q, k, md, Wq1, bq1, Wq2, bq2, gq, betaq,
                       Wk1, bk1, Wk2, bk2, gk, betak, ws);

    hipLaunchKernelGGL(fuse_kernel, dim3(BB * (PP / 256)), dim3(256), 0, stream,
                       v, mask, ws, out_fused, out_attn);
}